// Round 13
// baseline (49.192 us; speedup 1.0000x reference)
//
#include <hip/hip_runtime.h>

typedef float f32x4 __attribute__((ext_vector_type(4)));
typedef short s16x8 __attribute__((ext_vector_type(8)));

#define MFMA(a, b, c) __builtin_amdgcn_mfma_f32_16x16x32_bf16(a, b, c, 0, 0, 0)

__device__ __forceinline__ ushort f2bf(float f) {
    unsigned u = __float_as_uint(f);
    u += 0x7FFF + ((u >> 16) & 1);          // RNE to bf16
    return (ushort)(u >> 16);
}

// =============== K1: W -> B-frag planes (hi-re, hi-im only; 2 MB ws) ===============
// block=(r,i,nt), 64 blocks. ws layout: [mode 512][nt 2][plane 2][64 lanes x 16B].
__global__ __launch_bounds__(256) void w_prep(
    const float* __restrict__ w1_re, const float* __restrict__ w1_im,
    const float* __restrict__ w2_re, const float* __restrict__ w2_im,
    char* __restrict__ ws)
{
    const int tid = threadIdx.x, bid = blockIdx.x;
    const int r = bid >> 5, i = (bid >> 1) & 15, nt = bid & 1;
    const float* wre = r ? w2_re : w1_re;
    const float* wim = r ? w2_im : w1_im;
    const int col = tid >> 4, j = tid & 15, o = nt * 16 + col;
    const int modeLin = (r * 16 + i) * 16 + j;
    s16x8* pb = (s16x8*)ws;                  // 16B frag units; plane stride 64
    #pragma unroll
    for (int kg = 0; kg < 4; ++kg) {
        s16x8 hr, hi2;
        #pragma unroll
        for (int e = 0; e < 8; ++e) {
            int c = kg * 8 + e;
            long src = ((long)(c * 32 + o) * 16 + i) * 16 + j;
            hr[e]  = (short)f2bf(wre[src]);
            hi2[e] = (short)f2bf(wim[src]);
        }
        long base = (long)(modeLin * 2 + nt) * 128;
        pb[base + kg * 16 + col]      = hr;
        pb[base + 64 + kg * 16 + col] = hi2;
    }
}

// =============== K2: block = (r, nt, bl). 512 blocks, 2/CU ===============
// Owns out[bl, o-half, h-half, :] = 16 x 8448B line-aligned contiguous chunks.
// i loops INSIDE the block: 4 chunks x 4 h. A = x hi+lo (LDS), B = hi-only (ws).
__global__ __launch_bounds__(256, 2) void k_main(
    const float* __restrict__ x_re, const float* __restrict__ x_im,
    float* __restrict__ out, const char* __restrict__ ws)
{
    const int tid = threadIdx.x, bid = blockIdx.x;
    const int bl = bid & 127;
    const int rn = bid >> 7;                 // (r,nt) pairs of same bl are 128/256 apart -> same XCD
    const int r = rn & 1, nt = rn >> 1;
    const int hbase = r ? 48 : 0;
    const int obase = nt * 16;
    const int modeBase0 = r * 256;

    __shared__ ushort Afr[8192];             // [hl 4][j 16][p 4][c 32], 16 KB
    __shared__ float2 stg[2112];             // [hl 4][o 16][w 33], 16.9 KB

    const int lane = tid & 63, wave = tid >> 6;
    const int ks = lane >> 4, colo = lane & 15;
    const s16x8* BW = (const s16x8*)ws;

    // ---- prefetch B-frags for i=0 (this wave's 4 j) ----
    s16x8 cB[8], nB[8];                      // [jj*2 + plane]
    #pragma unroll
    for (int jj = 0; jj < 4; ++jj) {
        long mb = (long)((modeBase0 + wave * 4 + jj) * 2 + nt) * 128;
        cB[jj * 2 + 0] = BW[mb + lane];
        cB[jj * 2 + 1] = BW[mb + 64 + lane];
    }

    for (int ch = 0; ch < 4; ++ch) {
        // ---- stage x[bl, 32c, 4h, j<16] as A-frag hi/lo planes ----
        #pragma unroll
        for (int pass = 0; pass < 2; ++pass) {
            int u = pass * 256 + tid;        // (c, hl, j4)
            int j4 = u & 3, hl = (u >> 2) & 3, c = u >> 4;
            long sb = ((long)(bl * 32 + c) * 64 + hbase + ch * 4 + hl) * 33 + j4 * 4;
            int la = (hl * 16 + j4 * 4) * 128 + c;   // j stride 128, p stride 32
            #pragma unroll
            for (int q = 0; q < 4; ++q) {
                float re = x_re[sb + q], im = x_im[sb + q];
                ushort hr = f2bf(re);
                ushort lr = f2bf(re - __uint_as_float((unsigned)hr << 16));
                ushort hi = f2bf(im);
                ushort li = f2bf(im - __uint_as_float((unsigned)hi << 16));
                int a = la + q * 128;
                Afr[a] = hr; Afr[a + 32] = lr; Afr[a + 64] = hi; Afr[a + 96] = li;
            }
        }
        // ---- overlap: write previous chunk's staged output while stage lands ----
        if (ch > 0) {
            #pragma unroll 1
            for (int t = 0; t < 9; ++t) {
                int idx = t * 256 + tid;
                if (idx < 2112) {
                    int o = idx / 132;
                    int rem = idx - o * 132;
                    int hl = rem / 33, w = rem - hl * 33;
                    float2 v = (w < 16) ? stg[(hl * 16 + o) * 33 + w] : make_float2(0.f, 0.f);
                    long dst = ((long)(bl * 32 + obase + o) * 64 + hbase + (ch - 1) * 4 + hl) * 33 + w;
                    ((float2*)out)[dst] = v;
                }
            }
        }
        __syncthreads();                     // Afr ready, stg consumed

        // ---- compute: 4 h x 4 j per wave, B-pipeline one i ahead ----
        #pragma unroll
        for (int hl = 0; hl < 4; ++hl) {
            const int i = ch * 4 + hl;
            if (i < 15) {
                #pragma unroll
                for (int jj = 0; jj < 4; ++jj) {
                    long mb = (long)((modeBase0 + (i + 1) * 16 + wave * 4 + jj) * 2 + nt) * 128;
                    nB[jj * 2 + 0] = BW[mb + lane];
                    nB[jj * 2 + 1] = BW[mb + 64 + lane];
                }
            }
            #pragma unroll
            for (int jj = 0; jj < 4; ++jj) {
                const int j = wave * 4 + jj;
                const int ab = (hl * 16 + j) * 128 + ks * 8;
                s16x8 Ahr = *(const s16x8*)&Afr[ab];
                s16x8 Alr = *(const s16x8*)&Afr[ab + 32];
                s16x8 Ahi = *(const s16x8*)&Afr[ab + 64];
                s16x8 Ali = *(const s16x8*)&Afr[ab + 96];
                f32x4 accP = (f32x4)0.0f, accN = (f32x4)0.0f, accI = (f32x4)0.0f;
                accP = MFMA(Ahr, cB[jj * 2 + 0], accP);
                accP = MFMA(Alr, cB[jj * 2 + 0], accP);
                accN = MFMA(Ahi, cB[jj * 2 + 1], accN);
                accN = MFMA(Ali, cB[jj * 2 + 1], accN);
                accI = MFMA(Ahr, cB[jj * 2 + 1], accI);
                accI = MFMA(Alr, cB[jj * 2 + 1], accI);
                accI = MFMA(Ahi, cB[jj * 2 + 0], accI);
                accI = MFMA(Ali, cB[jj * 2 + 0], accI);
                if (lane < 16)               // D row 0 (M=1), col = o
                    stg[(hl * 16 + colo) * 33 + j] = make_float2(accP[0] - accN[0], accI[0]);
            }
            if (i < 15) {
                #pragma unroll
                for (int q = 0; q < 8; ++q) cB[q] = nB[q];
            }
        }
        __syncthreads();                     // stg complete; Afr free for next stage
    }

    // ---- last chunk's output ----
    #pragma unroll 1
    for (int t = 0; t < 9; ++t) {
        int idx = t * 256 + tid;
        if (idx < 2112) {
            int o = idx / 132;
            int rem = idx - o * 132;
            int hl = rem / 33, w = rem - hl * 33;
            float2 v = (w < 16) ? stg[(hl * 16 + o) * 33 + w] : make_float2(0.f, 0.f);
            long dst = ((long)(bl * 32 + obase + o) * 64 + hbase + 12 + hl) * 33 + w;
            ((float2*)out)[dst] = v;
        }
    }

    // ---- mid-zero band: h in [16,32) for r=0, [32,48) for r=1 (float4 streams) ----
    const int f4off = ((r ? 32 : 16) * 33) >> 1;    // 264 or 528
    float4* out4 = (float4*)out;
    const float4 z = make_float4(0.f, 0.f, 0.f, 0.f);
    #pragma unroll 1
    for (int t = 0; t < 17; ++t) {
        int idx = t * 256 + tid;             // 16 o x 264 f4 = 4224
        if (idx < 4224) {
            int o = idx >> 8;                // /264? no: use exact div
            o = idx / 264;
            int q = idx - o * 264;
            out4[(long)(bl * 32 + obase + o) * 1056 + f4off + q] = z;
        }
    }
}

extern "C" void kernel_launch(void* const* d_in, const int* in_sizes, int n_in,
                              void* d_out, int out_size, void* d_ws, size_t ws_size,
                              hipStream_t stream) {
    const float* x_re  = (const float*)d_in[0];
    const float* x_im  = (const float*)d_in[1];
    const float* w1_re = (const float*)d_in[2];
    const float* w1_im = (const float*)d_in[3];
    const float* w2_re = (const float*)d_in[4];
    const float* w2_im = (const float*)d_in[5];
    float* out = (float*)d_out;
    char* ws = (char*)d_ws;

    w_prep<<<dim3(64), dim3(256), 0, stream>>>(w1_re, w1_im, w2_re, w2_im, ws);
    k_main<<<dim3(512), dim3(256), 0, stream>>>(x_re, x_im, out, ws);
}

// Round 14
// 41.068 us; speedup vs baseline: 1.1978x; 1.1978x over previous
//
#include <hip/hip_runtime.h>

#define HW 2112L            // 64*33
typedef float f32x4 __attribute__((ext_vector_type(4)));
typedef short s16x8 __attribute__((ext_vector_type(8)));

// ws layout: W B-frag planes (4 x 1MB), then ws2 intermediate at 8MB.
#define WT_PLANE 1048576L
#define OFF_WHR 0L
#define OFF_WLR (WT_PLANE)
#define OFF_WHI (2*WT_PLANE)
#define OFF_WLI (3*WT_PLANE)
#define OFF_WS2 8388608L    // float2[128 bl][32 o][2 r][16 i][16 j] = 16.8 MB

__device__ __forceinline__ ushort f2bf(float f) {
    unsigned u = __float_as_uint(f);
    u += 0x7FFF + ((u >> 16) & 1);          // RNE to bf16
    return (ushort)(u >> 16);
}
__device__ __forceinline__ void split_bf(float v, ushort& hi, ushort& lo) {
    hi = f2bf(v);
    float hf = __uint_as_float(((unsigned)hi) << 16);
    lo = f2bf(v - hf);
}

// =============== K1: W -> B-frag planes (128 blocks, ~2.5us) ===============
__global__ __launch_bounds__(256) void w_prep(
    const float* __restrict__ w1_re, const float* __restrict__ w1_im,
    const float* __restrict__ w2_re, const float* __restrict__ w2_im,
    char* __restrict__ ws)
{
    const int tid = threadIdx.x, bid = blockIdx.x;
    const int r = bid >> 6, i = (bid >> 2) & 15, nt = (bid >> 1) & 1, kh = bid & 1;
    const float* wre = r ? w2_re : w1_re;
    const float* wim = r ? w2_im : w1_im;
    const int col = tid >> 4, j = tid & 15, o = nt * 16 + col;
    const int modeLin = (r * 16 + i) * 16 + j;
    s16x8* phr = (s16x8*)(ws + OFF_WHR);
    s16x8* plr = (s16x8*)(ws + OFF_WLR);
    s16x8* phi = (s16x8*)(ws + OFF_WHI);
    s16x8* pli = (s16x8*)(ws + OFF_WLI);
    #pragma unroll
    for (int kk = 0; kk < 2; ++kk) {
        const int kg = kh * 2 + kk;
        s16x8 hr, lr, hi2, li2;
        #pragma unroll
        for (int e = 0; e < 8; ++e) {
            int c = kg * 8 + e;
            long src = ((long)(c * 32 + o) * 16 + i) * 16 + j;
            ushort a, b;
            split_bf(wre[src], a, b); hr[e] = (short)a; lr[e] = (short)b;
            split_bf(wim[src], a, b); hi2[e] = (short)a; li2[e] = (short)b;
        }
        long off = (long)(modeLin * 2 + nt) * 64 + kg * 16 + col;
        phr[off] = hr; plr[off] = lr; phi[off] = hi2; pli[off] = li2;
    }
}

// =============== K2: compute -> compact ws2 (1024 blocks, linear writes) ===============
__global__ __launch_bounds__(256, 4) void k_compute(
    const float* __restrict__ x_re, const float* __restrict__ x_im,
    char* __restrict__ ws)
{
    const int tid = threadIdx.x, bid = blockIdx.x;
    const int r = bid >> 9, i = (bid >> 5) & 15, bt = bid & 31;
    const int h = r ? 48 + i : i;
    const int bl0 = bt * 4;
    const int modeBase = (r * 16 + i) * 16;

    __shared__ __align__(16) ushort xfr[16][4][32];   // [j][bl][c] bf16 hi of re
    __shared__ __align__(16) ushort xfi[16][4][32];
    __shared__ __align__(16) float2 stg[128][17];     // [bl*32+o][j]

    const int wave = tid >> 6, lane = tid & 63;
    const int m = lane & 3, ks = lane >> 4, colo = lane & 15;

    const s16x8* Bwhr = (const s16x8*)(ws + OFF_WHR);
    const s16x8* Bwlr = (const s16x8*)(ws + OFF_WLR);
    const s16x8* Bwhi = (const s16x8*)(ws + OFF_WHI);
    const s16x8* Bwli = (const s16x8*)(ws + OFF_WLI);

    // ---- prefetch B-frags for jj=0 (independent of LDS stage) ----
    const int j0 = wave * 4;
    s16x8 cBhr[2], cBlr[2], cBhi[2], cBli[2];
    {
        long b0 = ((long)(modeBase + j0) * 2 + 0) * 64 + lane;
        long b1 = ((long)(modeBase + j0) * 2 + 1) * 64 + lane;
        cBhr[0] = Bwhr[b0]; cBlr[0] = Bwlr[b0]; cBhi[0] = Bwhi[b0]; cBli[0] = Bwli[b0];
        cBhr[1] = Bwhr[b1]; cBlr[1] = Bwlr[b1]; cBhi[1] = Bwhi[b1]; cBli[1] = Bwli[b1];
    }

    // ---- stage x[bl0..+4, all c, h, j<16]: coalesced, bf16-split at stage time ----
    #pragma unroll
    for (int p = 0; p < 2; ++p) {
        int idx = p * 256 + tid;            // [0,512)
        int j4 = idx & 3, row = idx >> 2;   // c=row>>2, bl=row&3
        int c = row >> 2, bl = row & 3;
        long base = ((long)((bl0 + bl) * 32 + c)) * HW + h * 33 + j4 * 4;
        float re0 = x_re[base + 0], re1 = x_re[base + 1], re2 = x_re[base + 2], re3 = x_re[base + 3];
        float im0 = x_im[base + 0], im1 = x_im[base + 1], im2 = x_im[base + 2], im3 = x_im[base + 3];
        xfr[j4 * 4 + 0][bl][c] = f2bf(re0); xfi[j4 * 4 + 0][bl][c] = f2bf(im0);
        xfr[j4 * 4 + 1][bl][c] = f2bf(re1); xfi[j4 * 4 + 1][bl][c] = f2bf(im1);
        xfr[j4 * 4 + 2][bl][c] = f2bf(re2); xfi[j4 * 4 + 2][bl][c] = f2bf(im2);
        xfr[j4 * 4 + 3][bl][c] = f2bf(re3); xfi[j4 * 4 + 3][bl][c] = f2bf(im3);
    }
    __syncthreads();

    #pragma unroll
    for (int jj = 0; jj < 4; ++jj) {
        const int j = j0 + jj;

        s16x8 nBhr[2], nBlr[2], nBhi[2], nBli[2];
        if (jj < 3) {
            long b0 = ((long)(modeBase + j + 1) * 2 + 0) * 64 + lane;
            long b1 = ((long)(modeBase + j + 1) * 2 + 1) * 64 + lane;
            nBhr[0] = Bwhr[b0]; nBlr[0] = Bwlr[b0]; nBhi[0] = Bwhi[b0]; nBli[0] = Bwli[b0];
            nBhr[1] = Bwhr[b1]; nBlr[1] = Bwlr[b1]; nBhi[1] = Bwhi[b1]; nBli[1] = Bwli[b1];
        }

        s16x8 Ahr = *(const s16x8*)&xfr[j][m][ks * 8];
        s16x8 Ahi = *(const s16x8*)&xfi[j][m][ks * 8];

        #pragma unroll
        for (int nt = 0; nt < 2; ++nt) {
            f32x4 accP = (f32x4)0.0f, accN = (f32x4)0.0f, accI = (f32x4)0.0f;
            accP = __builtin_amdgcn_mfma_f32_16x16x32_bf16(Ahr, cBhr[nt], accP, 0, 0, 0);
            accP = __builtin_amdgcn_mfma_f32_16x16x32_bf16(Ahr, cBlr[nt], accP, 0, 0, 0);
            accN = __builtin_amdgcn_mfma_f32_16x16x32_bf16(Ahi, cBhi[nt], accN, 0, 0, 0);
            accN = __builtin_amdgcn_mfma_f32_16x16x32_bf16(Ahi, cBli[nt], accN, 0, 0, 0);
            accI = __builtin_amdgcn_mfma_f32_16x16x32_bf16(Ahr, cBhi[nt], accI, 0, 0, 0);
            accI = __builtin_amdgcn_mfma_f32_16x16x32_bf16(Ahr, cBli[nt], accI, 0, 0, 0);
            accI = __builtin_amdgcn_mfma_f32_16x16x32_bf16(Ahi, cBhr[nt], accI, 0, 0, 0);
            accI = __builtin_amdgcn_mfma_f32_16x16x32_bf16(Ahi, cBlr[nt], accI, 0, 0, 0);

            if (ks == 0) {
                #pragma unroll
                for (int q = 0; q < 4; ++q)
                    stg[q * 32 + nt * 16 + colo][j] =
                        make_float2(accP[q] - accN[q], accI[q]);
            }
        }

        if (jj < 3) {
            #pragma unroll
            for (int nt = 0; nt < 2; ++nt) {
                cBhr[nt] = nBhr[nt]; cBlr[nt] = nBlr[nt];
                cBhi[nt] = nBhi[nt]; cBli[nt] = nBli[nt];
            }
        }
    }
    __syncthreads();

    // ---- linear writeout: ws2[bl][o][r][i][j], 128B full-line runs ----
    float2* W2 = (float2*)(ws + OFF_WS2);
    const long base = (long)bl0 * 32 * 512 + r * 256 + i * 16;
    #pragma unroll
    for (int p = 0; p < 8; ++p) {
        int idx = p * 256 + tid;            // [0,2048)
        int j = idx & 15, o = (idx >> 4) & 31, blq = idx >> 9;
        W2[base + (long)blq * 16384 + o * 512 + j] = stg[blq * 32 + o][j];
    }
}

// =============== K3: placer — stream entire output (512 blocks) ===============
// block=(bl, oq): owns 8 full 16896B (bl,o)-planes; corner data from ws2, zeros else.
__global__ __launch_bounds__(256) void k_place(
    float* __restrict__ out, const char* __restrict__ ws)
{
    const int tid = threadIdx.x, bid = blockIdx.x;
    const int bl = bid >> 2, oq = bid & 3;
    const float2* W2 = (const float2*)(ws + OFF_WS2);
    float4* out4 = (float4*)out;
    const long outbase4 = ((long)bl * 32 + oq * 8) * 1056;   // float4 units
    const long wbase    = ((long)bl * 32 + oq * 8) * 512;    // float2 units

    #pragma unroll 1
    for (int p = 0; p < 33; ++p) {
        int idx = p * 256 + tid;            // [0, 8448) float4 across 8 planes
        int ol = idx / 1056;
        int f  = idx - ol * 1056;
        int g0 = f * 2, g1 = g0 + 1;        // float2 slots in plane
        int h0 = g0 / 33, w0 = g0 - h0 * 33;
        int h1 = g1 / 33, w1 = g1 - h1 * 33;
        float4 v = make_float4(0.f, 0.f, 0.f, 0.f);
        if (w0 < 16 && (h0 < 16 || h0 >= 48)) {
            float2 t = W2[wbase + (long)ol * 512 + (h0 < 16 ? h0 * 16 : 256 + (h0 - 48) * 16) + w0];
            v.x = t.x; v.y = t.y;
        }
        if (w1 < 16 && (h1 < 16 || h1 >= 48)) {
            float2 t = W2[wbase + (long)ol * 512 + (h1 < 16 ? h1 * 16 : 256 + (h1 - 48) * 16) + w1];
            v.z = t.x; v.w = t.y;
        }
        out4[outbase4 + (long)ol * 1056 + f] = v;
    }
}

extern "C" void kernel_launch(void* const* d_in, const int* in_sizes, int n_in,
                              void* d_out, int out_size, void* d_ws, size_t ws_size,
                              hipStream_t stream) {
    const float* x_re  = (const float*)d_in[0];
    const float* x_im  = (const float*)d_in[1];
    const float* w1_re = (const float*)d_in[2];
    const float* w1_im = (const float*)d_in[3];
    const float* w2_re = (const float*)d_in[4];
    const float* w2_im = (const float*)d_in[5];
    float* out = (float*)d_out;
    char* ws = (char*)d_ws;

    w_prep<<<dim3(128), dim3(256), 0, stream>>>(w1_re, w1_im, w2_re, w2_im, ws);
    k_compute<<<dim3(1024), dim3(256), 0, stream>>>(x_re, x_im, ws);
    k_place<<<dim3(512), dim3(256), 0, stream>>>(out, ws);
}

// Round 15
// 38.741 us; speedup vs baseline: 1.2698x; 1.0601x over previous
//
#include <hip/hip_runtime.h>

typedef float f32x4 __attribute__((ext_vector_type(4)));
typedef short s16x8 __attribute__((ext_vector_type(8)));

#define MFMA(a, b, c) __builtin_amdgcn_mfma_f32_16x16x32_bf16(a, b, c, 0, 0, 0)

__device__ __forceinline__ ushort f2bf(float f) {
    unsigned u = __float_as_uint(f);
    u += 0x7FFF + ((u >> 16) & 1);          // RNE to bf16
    return (ushort)(u >> 16);
}

// =============== K1: W -> B-frag planes (hi-re, hi-im only; 2 MB ws) ===============
// block=(r,i,nt), 64 blocks. ws: [mode 512][nt 2][pl 2][64 lanes x 16B].
__global__ __launch_bounds__(256) void w_prep(
    const float* __restrict__ w1_re, const float* __restrict__ w1_im,
    const float* __restrict__ w2_re, const float* __restrict__ w2_im,
    char* __restrict__ ws)
{
    const int tid = threadIdx.x, bid = blockIdx.x;
    const int r = bid >> 5, i = (bid >> 1) & 15, nt = bid & 1;
    const float* wre = r ? w2_re : w1_re;
    const float* wim = r ? w2_im : w1_im;
    const int col = tid >> 4, j = tid & 15, o = nt * 16 + col;
    const int modeLin = (r * 16 + i) * 16 + j;
    s16x8* pb = (s16x8*)ws;
    #pragma unroll
    for (int kg = 0; kg < 4; ++kg) {
        s16x8 hr, hi2;
        #pragma unroll
        for (int e = 0; e < 8; ++e) {
            int c = kg * 8 + e;
            long src = ((long)(c * 32 + o) * 16 + i) * 16 + j;
            hr[e]  = (short)f2bf(wre[src]);
            hi2[e] = (short)f2bf(wim[src]);
        }
        long base = (long)(modeLin * 2 + nt) * 128;
        pb[base + kg * 16 + col]      = hr;
        pb[base + 64 + kg * 16 + col] = hi2;
    }
}

// =============== K2: 512 blocks x 512 threads, block = (r, nt, bl) ===============
// Owns out[bl, 16 o, 16 corner h, all w] + its mid-band share: line-aligned, zero RMW.
// 4 chunks x 4 h. A = x hi+lo (LDS, bank-clean), B = hi-only (ws, hl-pipelined regs).
__global__ __launch_bounds__(512, 4) void k_main(
    const float* __restrict__ x_re, const float* __restrict__ x_im,
    float* __restrict__ out, const char* __restrict__ ws)
{
    const int tid = threadIdx.x, bid = blockIdx.x;
    const int bl = bid & 127;
    const int rn = bid >> 7;
    const int r = rn & 1, nt = rn >> 1;
    const int hbase = r ? 48 : 0;
    const int obase = nt * 16;
    const int modeBase0 = r * 256;

    __shared__ float  xs_re[4][32][17];       // 8.5 KB  (17 coprime 32: conflict-free)
    __shared__ float  xs_im[4][32][17];       // 8.5 KB
    __shared__ ushort Afr[4][16][4][32];      // [hl][j][pl hr,lr,hi,li][c] 16 KB
    __shared__ float2 stg[4][16][17];         // [hl][o][j] 8.5 KB

    const int lane = tid & 63, wave = tid >> 6;
    const int ks = lane >> 4, colo = lane & 15;
    const s16x8* BW = (const s16x8*)ws;
    float2* out2 = (float2*)out;

    // ---- prefetch B for i=0 (this wave's 2 j) ----
    s16x8 cB[2][2], nB[2][2];
    #pragma unroll
    for (int jj = 0; jj < 2; ++jj) {
        long mb = (long)((modeBase0 + wave * 2 + jj) * 2 + nt) * 128;
        cB[jj][0] = BW[mb + lane];
        cB[jj][1] = BW[mb + 64 + lane];
    }

    for (int ch = 0; ch < 4; ++ch) {
        // ---- stage: x[bl, 32c, 4h, 16j] -> xs (j-fastest lanes, 64B runs) ----
        {
            int j4 = tid & 3, c = (tid >> 2) & 31, hl = tid >> 7;
            long sb = ((long)(bl * 32 + c) * 64 + hbase + ch * 4 + hl) * 33 + j4 * 4;
            f32x4 vr = *(const f32x4*)&x_re[sb];
            f32x4 vi = *(const f32x4*)&x_im[sb];
            #pragma unroll
            for (int q = 0; q < 4; ++q) {
                xs_re[hl][c][j4 * 4 + q] = vr[q];
                xs_im[hl][c][j4 * 4 + q] = vi[q];
            }
        }
        __syncthreads();                          // xs ready

        // ---- transpose: c-inner lanes read xs (conflict-free), split, store frags
        //      c-inner stores -> each wave writes contiguous 128B runs (free) ----
        #pragma unroll
        for (int it = 0; it < 4; ++it) {
            int u = it * 512 + tid;
            int c = u & 31, j = (u >> 5) & 15, hl = u >> 9;
            float re = xs_re[hl][c][j], im = xs_im[hl][c][j];
            ushort hr = f2bf(re);
            ushort lr = f2bf(re - __uint_as_float((unsigned)hr << 16));
            ushort hi = f2bf(im);
            ushort li = f2bf(im - __uint_as_float((unsigned)hi << 16));
            Afr[hl][j][0][c] = hr; Afr[hl][j][1][c] = lr;
            Afr[hl][j][2][c] = hi; Afr[hl][j][3][c] = li;
        }
        __syncthreads();                          // Afr ready

        // ---- compute: 4 hl x 2 j per wave; B pipelined one i ahead ----
        #pragma unroll
        for (int hl = 0; hl < 4; ++hl) {
            const int i = ch * 4 + hl;
            if (i < 15) {
                #pragma unroll
                for (int jj = 0; jj < 2; ++jj) {
                    long mb = (long)((modeBase0 + (i + 1) * 16 + wave * 2 + jj) * 2 + nt) * 128;
                    nB[jj][0] = BW[mb + lane];
                    nB[jj][1] = BW[mb + 64 + lane];
                }
            }
            #pragma unroll
            for (int jj = 0; jj < 2; ++jj) {
                const int j = wave * 2 + jj;
                s16x8 Ahr = *(const s16x8*)&Afr[hl][j][0][ks * 8];
                s16x8 Alr = *(const s16x8*)&Afr[hl][j][1][ks * 8];
                s16x8 Ahi = *(const s16x8*)&Afr[hl][j][2][ks * 8];
                s16x8 Ali = *(const s16x8*)&Afr[hl][j][3][ks * 8];
                f32x4 accP = (f32x4)0.0f, accN = (f32x4)0.0f, accI = (f32x4)0.0f;
                accP = MFMA(Ahr, cB[jj][0], accP);
                accP = MFMA(Alr, cB[jj][0], accP);
                accN = MFMA(Ahi, cB[jj][1], accN);
                accN = MFMA(Ali, cB[jj][1], accN);
                accI = MFMA(Ahr, cB[jj][1], accI);
                accI = MFMA(Alr, cB[jj][1], accI);
                accI = MFMA(Ahi, cB[jj][0], accI);
                accI = MFMA(Ali, cB[jj][0], accI);
                if (lane < 16)                    // M=1: D row 0, col = o
                    stg[hl][colo][j] = make_float2(accP[0] - accN[0], accI[0]);
            }
            if (i < 15) {
                #pragma unroll
                for (int jj = 0; jj < 2; ++jj) {
                    cB[jj][0] = nB[jj][0];
                    cB[jj][1] = nB[jj][1];
                }
            }
        }
        __syncthreads();                          // stg ready

        // ---- writeout: 16 o x (4h x 33w contiguous 1056B runs), tails fused ----
        #pragma unroll
        for (int t = 0; t < 5; ++t) {
            int idx = t * 512 + tid;              // [0, 2560); valid < 2112
            if (idx < 2112) {
                int o = idx / 132;
                int rem = idx - o * 132;
                int hl2 = rem / 33, w = rem - hl2 * 33;
                float2 v = (w < 16) ? stg[hl2][o][w] : make_float2(0.f, 0.f);
                long dst = ((long)(bl * 32 + obase + o) * 64 + hbase + ch * 4 + hl2) * 33 + w;
                out2[dst] = v;
            }
        }
        // next stage overwrites xs only after barrier(next); stg reused after barrier2(next)
    }

    // ---- mid-band zeros: r=0 -> h[16,32), r=1 -> h[32,48); 16 o x 264 float4 ----
    {
        float4* out4 = (float4*)out;
        const float4 z = make_float4(0.f, 0.f, 0.f, 0.f);
        const int midoff = r ? 528 : 264;         // float4 offset of band start
        #pragma unroll
        for (int t = 0; t < 9; ++t) {
            int idx = t * 512 + tid;              // [0, 4608); valid < 4224
            if (idx < 4224) {
                int o = idx / 264;
                int q = idx - o * 264;
                out4[(long)(bl * 32 + obase + o) * 1056 + midoff + q] = z;
            }
        }
    }
}

extern "C" void kernel_launch(void* const* d_in, const int* in_sizes, int n_in,
                              void* d_out, int out_size, void* d_ws, size_t ws_size,
                              hipStream_t stream) {
    const float* x_re  = (const float*)d_in[0];
    const float* x_im  = (const float*)d_in[1];
    const float* w1_re = (const float*)d_in[2];
    const float* w1_im = (const float*)d_in[3];
    const float* w2_re = (const float*)d_in[4];
    const float* w2_im = (const float*)d_in[5];
    float* out = (float*)d_out;
    char* ws = (char*)d_ws;

    w_prep<<<dim3(64), dim3(256), 0, stream>>>(w1_re, w1_im, w2_re, w2_im, ws);
    k_main<<<dim3(512), dim3(512), 0, stream>>>(x_re, x_im, out, ws);
}